// Round 1
// baseline (86.289 us; speedup 1.0000x reference)
//
#include <hip/hip_runtime.h>

#define NCH 16          // feature channels F
#define TLEN 2048       // time length T
#define NTHREADS 256

// One block per batch element.
// Phases:
//  A: chunk sums (8 positions/thread, 16 ch)            -> sA[256][16]
//  B: Hillis-Steele inclusive scan over 256 chunks      -> prefix at 8-granularity
//  C: exact prefixes at 13 clusters x 16-pos windows    -> Tt[208][17]
//  D: 72 pooled stage-a values via prefix differences   -> faL[6][12]
//  E: stage-b conv + pool + leaky + FC                  -> out[b]
__global__ __launch_bounds__(NTHREADS) void filternet_kernel(
    const float* __restrict__ x,
    const float* __restrict__ wa1, const float* __restrict__ wa2,
    const float* __restrict__ wa3, const float* __restrict__ wa4,
    const float* __restrict__ wa5, const float* __restrict__ wa6,
    const float* __restrict__ wb1, const float* __restrict__ wb2,
    const float* __restrict__ wb3, const float* __restrict__ wb4,
    const float* __restrict__ wb5, const float* __restrict__ wb6,
    const float* __restrict__ wfc, float* __restrict__ out, int nb)
{
    __shared__ float sA[NTHREADS][NCH];
    __shared__ float sB[NTHREADS][NCH];
    __shared__ float Tt[13 * 16][NCH + 1];   // padded
    __shared__ float waL[6][NCH][6];
    __shared__ float wbL[6][6];
    __shared__ float wfcL[108];
    __shared__ float faL[6][12];
    __shared__ float partial[6];

    const int tid = threadIdx.x;
    const int b = blockIdx.x;
    if (b >= nb) return;
    const float* __restrict__ xb = x + (size_t)b * (TLEN * NCH);

    // ---- weights -> LDS (used only in phases D/E; barrier below covers it)
    if (tid < 96) {
        const int k0 = tid >> 4, c = tid & 15, K = k0 + 1;
        const float* w = (k0 == 0) ? wa1 : (k0 == 1) ? wa2 : (k0 == 2) ? wa3
                       : (k0 == 3) ? wa4 : (k0 == 4) ? wa5 : wa6;
        for (int j = 0; j < 6; ++j)
            waL[k0][c][j] = (j < K) ? w[c * K + j] : 0.0f;
    } else if (tid < 102) {
        const int k0 = tid - 96, K = k0 + 1;
        const float* w = (k0 == 0) ? wb1 : (k0 == 1) ? wb2 : (k0 == 2) ? wb3
                       : (k0 == 3) ? wb4 : (k0 == 4) ? wb5 : wb6;
        for (int j = 0; j < 6; ++j)
            wbL[k0][j] = (j < K) ? w[j] : 0.0f;
    } else if (tid >= 128 && tid < 236) {
        wfcL[tid - 128] = wfc[tid - 128];
    }

    // ---- phase A: per-thread chunk sums over 8 consecutive positions
    {
        float accv[NCH];
#pragma unroll
        for (int c = 0; c < NCH; ++c) accv[c] = 0.0f;
        const float4* x4 = reinterpret_cast<const float4*>(xb) + (size_t)tid * 32;
#pragma unroll
        for (int p = 0; p < 8; ++p) {
#pragma unroll
            for (int g = 0; g < 4; ++g) {
                float4 v = x4[p * 4 + g];
                accv[g * 4 + 0] += v.x;
                accv[g * 4 + 1] += v.y;
                accv[g * 4 + 2] += v.z;
                accv[g * 4 + 3] += v.w;
            }
        }
#pragma unroll
        for (int c = 0; c < NCH; ++c) sA[tid][c] = accv[c];
    }
    __syncthreads();

    // ---- phase B: inclusive scan over 256 chunks, per channel (ping-pong)
    float (*scanRes)[NCH];
    {
        float (*src)[NCH] = sA;
        float (*dst)[NCH] = sB;
        for (int step = 1; step < 256; step <<= 1) {
#pragma unroll
            for (int t2 = 0; t2 < 16; ++t2) {
                const int eid = t2 * NTHREADS + tid;   // 0..4095
                const int j = eid >> 4;
                const int c = eid & 15;
                float v = src[j][c];
                if (j >= step) v += src[j - step][c];
                dst[j][c] = v;
            }
            __syncthreads();
            float (*tmp)[NCH] = src; src = dst; dst = tmp;
        }
        scanRes = src;   // inclusive chunk prefix
    }

    // ---- phase C: exact prefixes at cluster windows
    // cluster ci in [0,13): base = (ci==0) ? 0 : ci*2043/12 - 1, window of 16
    if (tid < 13 * 16) {
        const int ci = tid >> 4, off = tid & 15;
        const int cb = (ci == 0) ? 0 : (ci * 2043) / 12 - 1;
        const int p = cb + off;
        float tv[NCH];
        if (p <= TLEN) {
            const int j0 = p >> 3;
#pragma unroll
            for (int c = 0; c < NCH; ++c)
                tv[c] = (j0 > 0) ? scanRes[j0 - 1][c] : 0.0f;
            for (int t = j0 * 8; t < p; ++t) {
                const float4* xr = reinterpret_cast<const float4*>(xb + (size_t)t * NCH);
#pragma unroll
                for (int g = 0; g < 4; ++g) {
                    float4 v = xr[g];
                    tv[g * 4 + 0] += v.x;
                    tv[g * 4 + 1] += v.y;
                    tv[g * 4 + 2] += v.z;
                    tv[g * 4 + 3] += v.w;
                }
            }
        } else {
#pragma unroll
            for (int c = 0; c < NCH; ++c) tv[c] = 0.0f;
        }
#pragma unroll
        for (int c = 0; c < NCH; ++c) Tt[tid][c] = tv[c];
    }
    __syncthreads();

    // ---- phase D: 72 pooled stage-a values
    // pooled_sum[k][i] = sum_j sum_c wa_k[c,j]*(P[e+j][c]-P[s+j][c])
    if (tid < 72) {
        const int k0 = tid / 12, i = tid % 12, K = k0 + 1;
        const int L = TLEN - k0;
        const int s = (i * L) / 12;
        const int e = ((i + 1) * L + 11) / 12;   // ceil((i+1)L/12)
        const int n = e - s;
        const int cbs = (i == 0) ? 0 : (i * 2043) / 12 - 1;
        const int cbe = ((i + 1) * 2043) / 12 - 1;
        const int rs = i * 16 + (s - cbs);
        const int re = (i + 1) * 16 + (e - cbe);
        float acc2 = 0.0f;
        for (int j = 0; j < K; ++j) {
#pragma unroll
            for (int c = 0; c < NCH; ++c)
                acc2 += waL[k0][c][j] * (Tt[re + j][c] - Tt[rs + j][c]);
        }
        float v = acc2 / (float)n;
        faL[k0][i] = (v >= 0.0f) ? v : 0.1f * v;
    }
    __syncthreads();

    // ---- phase E: stage-b conv(dil=2) + pool(lb->6) + leaky + FC partials
    if (tid < 6) {
        const int k0 = tid, K = k0 + 1;
        const int lb = 12 - 2 * k0;
        float fbv[12];
        for (int l = 0; l < lb; ++l) {
            float a = 0.0f;
            for (int j = 0; j < K; ++j) a += wbL[k0][j] * faL[k0][l + 2 * j];
            fbv[l] = a;
        }
        float part = 0.0f;
        for (int i2 = 0; i2 < 12; ++i2)
            part += faL[k0][i2] * wfcL[k0 * 18 + i2];
        for (int i6 = 0; i6 < 6; ++i6) {
            const int s6 = (i6 * lb) / 6;
            const int e6 = ((i6 + 1) * lb + 5) / 6;
            float v = 0.0f;
            for (int l = s6; l < e6; ++l) v += fbv[l];
            v /= (float)(e6 - s6);
            v = (v >= 0.0f) ? v : 0.1f * v;
            part += v * wfcL[k0 * 18 + 12 + i6];
        }
        partial[k0] = part;
    }
    __syncthreads();

    if (tid == 0) {
        out[b] = partial[0] + partial[1] + partial[2] +
                 partial[3] + partial[4] + partial[5];
    }
}

extern "C" void kernel_launch(void* const* d_in, const int* in_sizes, int n_in,
                              void* d_out, int out_size, void* d_ws, size_t ws_size,
                              hipStream_t stream) {
    // Robust input assignment by element count:
    //   x: B*2048*16, wa_k: 16*k (16..96), wb_k: k (1..6), wfc: 108
    const float* x = nullptr;
    const float* wa[6] = {nullptr};
    const float* wb[6] = {nullptr};
    const float* wfc = nullptr;
    int nb = 0;
    for (int i = 0; i < n_in; ++i) {
        const int sz = in_sizes[i];
        const float* p = (const float*)d_in[i];
        if (sz >= TLEN * NCH) { x = p; nb = sz / (TLEN * NCH); }
        else if (sz == 108)   { wfc = p; }
        else if (sz % NCH == 0 && sz >= NCH && sz <= 6 * NCH) { wa[sz / NCH - 1] = p; }
        else if (sz >= 1 && sz <= 6) { wb[sz - 1] = p; }
    }

    float* outp = (float*)d_out;
    dim3 grid(nb), block(NTHREADS);
    hipLaunchKernelGGL(filternet_kernel, grid, block, 0, stream,
                       x, wa[0], wa[1], wa[2], wa[3], wa[4], wa[5],
                       wb[0], wb[1], wb[2], wb[3], wb[4], wb[5],
                       wfc, outp, nb);
}

// Round 2
// 82.430 us; speedup vs baseline: 1.0468x; 1.0468x over previous
//
#include <hip/hip_runtime.h>

#define NCH 16          // feature channels F
#define TLEN 2048       // time length T
#define NTHREADS 256

// One block per batch element.
// Phases:
//  A : chunk sums (8 contiguous positions/thread, 16 ch)      -> sA[256][.]
//  B1: segment sums (16 chunks = 128 positions each)          -> sSeg[16][16]
//  C : exact prefixes at 13 clusters x 16 positions via
//      segs + chunks + incremental x re-reads                 -> Tt[208][.]
//  D : 72 pooled stage-a values via prefix differences        -> faL[6][12]
//  E : stage-b conv + pool + leaky + FC                       -> out[b]
__global__ __launch_bounds__(NTHREADS, 4) void filternet_kernel(
    const float* __restrict__ x,
    const float* __restrict__ wa1, const float* __restrict__ wa2,
    const float* __restrict__ wa3, const float* __restrict__ wa4,
    const float* __restrict__ wa5, const float* __restrict__ wa6,
    const float* __restrict__ wb1, const float* __restrict__ wb2,
    const float* __restrict__ wb3, const float* __restrict__ wb4,
    const float* __restrict__ wb5, const float* __restrict__ wb6,
    const float* __restrict__ wfc, float* __restrict__ out, int nb)
{
    __shared__ float sA[NTHREADS][NCH + 1];   // chunk sums (8 pos), padded
    __shared__ float sSeg[16][NCH];           // segment sums (128 pos)
    __shared__ float Tt[13 * 16][NCH + 1];    // exact prefixes, padded
    __shared__ float waL[6][NCH][6];
    __shared__ float wbL[6][6];
    __shared__ float wfcL[108];
    __shared__ float faL[6][12];
    __shared__ float partial[6];

    const int tid = threadIdx.x;
    const int b = blockIdx.x;
    if (b >= nb) return;
    const float* __restrict__ xb = x + (size_t)b * (TLEN * NCH);

    // ---- weights -> LDS (consumed in phases D/E; A->B1 barrier covers it)
    if (tid < 96) {
        const int k0 = tid >> 4, c = tid & 15, K = k0 + 1;
        const float* w = (k0 == 0) ? wa1 : (k0 == 1) ? wa2 : (k0 == 2) ? wa3
                       : (k0 == 3) ? wa4 : (k0 == 4) ? wa5 : wa6;
        for (int j = 0; j < 6; ++j)
            waL[k0][c][j] = (j < K) ? w[c * K + j] : 0.0f;
    } else if (tid < 102) {
        const int k0 = tid - 96, K = k0 + 1;
        const float* w = (k0 == 0) ? wb1 : (k0 == 1) ? wb2 : (k0 == 2) ? wb3
                       : (k0 == 3) ? wb4 : (k0 == 4) ? wb5 : wb6;
        for (int j = 0; j < 6; ++j)
            wbL[k0][j] = (j < K) ? w[j] : 0.0f;
    } else if (tid >= 128 && tid < 236) {
        wfcL[tid - 128] = wfc[tid - 128];
    }

    // ---- phase A: per-thread chunk sums over 8 consecutive positions
    {
        float accv[NCH];
#pragma unroll
        for (int c = 0; c < NCH; ++c) accv[c] = 0.0f;
        const float4* x4 = reinterpret_cast<const float4*>(xb) + (size_t)tid * 32;
#pragma unroll
        for (int p = 0; p < 8; ++p) {
#pragma unroll
            for (int g = 0; g < 4; ++g) {
                float4 v = x4[p * 4 + g];
                accv[g * 4 + 0] += v.x;
                accv[g * 4 + 1] += v.y;
                accv[g * 4 + 2] += v.z;
                accv[g * 4 + 3] += v.w;
            }
        }
#pragma unroll
        for (int c = 0; c < NCH; ++c) sA[tid][c] = accv[c];
    }
    __syncthreads();

    // ---- phase B1: segment sums (16 chunks each)
    {
        const int s = tid >> 4, c = tid & 15;
        float v = 0.0f;
#pragma unroll
        for (int u = 0; u < 16; ++u) v += sA[s * 16 + u][c];
        sSeg[s][c] = v;
    }
    __syncthreads();

    // ---- phase C: exact prefixes at cluster windows (no full scan)
    // cluster ci in [0,13): base cb = (ci==0) ? 0 : ci*2043/12 - 1; 16 positions
    if (tid < 13 * 16) {
        const int ci = tid >> 4, c = tid & 15;
        const int cb = (ci == 0) ? 0 : (ci * 2043) / 12 - 1;
        const int j0 = cb >> 3;     // chunks fully below cb
        const int sb = j0 >> 4;     // segments fully below
        float run = 0.0f;
        for (int s = 0; s < sb; ++s) run += sSeg[s][c];
        for (int j = sb * 16; j < j0; ++j) run += sA[j][c];
        for (int t = j0 * 8; t < cb; ++t) run += xb[(size_t)t * NCH + c];
        // run == P[cb][c]; walk the 16 window positions incrementally
#pragma unroll
        for (int off = 0; off < 16; ++off) {
            Tt[ci * 16 + off][c] = run;
            const int p = cb + off;
            if (p < TLEN) run += xb[(size_t)p * NCH + c];
        }
    }
    __syncthreads();

    // ---- phase D: 72 pooled stage-a values
    // pooled_sum[k][i] = sum_j sum_c wa_k[c,j]*(P[e+j][c]-P[s+j][c])
    if (tid < 72) {
        const int k0 = tid / 12, i = tid % 12, K = k0 + 1;
        const int L = TLEN - k0;
        const int s = (i * L) / 12;
        const int e = ((i + 1) * L + 11) / 12;   // ceil((i+1)L/12)
        const int n = e - s;
        const int cbs = (i == 0) ? 0 : (i * 2043) / 12 - 1;
        const int cbe = ((i + 1) * 2043) / 12 - 1;
        const int rs = i * 16 + (s - cbs);
        const int re = (i + 1) * 16 + (e - cbe);
        float acc2 = 0.0f;
        for (int j = 0; j < K; ++j) {
#pragma unroll
            for (int c = 0; c < NCH; ++c)
                acc2 += waL[k0][c][j] * (Tt[re + j][c] - Tt[rs + j][c]);
        }
        float v = acc2 / (float)n;
        faL[k0][i] = (v >= 0.0f) ? v : 0.1f * v;
    }
    __syncthreads();

    // ---- phase E: stage-b conv(dil=2) + pool(lb->6) + leaky + FC partials
    if (tid < 6) {
        const int k0 = tid, K = k0 + 1;
        const int lb = 12 - 2 * k0;
        float fbv[12];
        for (int l = 0; l < lb; ++l) {
            float a = 0.0f;
            for (int j = 0; j < K; ++j) a += wbL[k0][j] * faL[k0][l + 2 * j];
            fbv[l] = a;
        }
        float part = 0.0f;
        for (int i2 = 0; i2 < 12; ++i2)
            part += faL[k0][i2] * wfcL[k0 * 18 + i2];
        for (int i6 = 0; i6 < 6; ++i6) {
            const int s6 = (i6 * lb) / 6;
            const int e6 = ((i6 + 1) * lb + 5) / 6;
            float v = 0.0f;
            for (int l = s6; l < e6; ++l) v += fbv[l];
            v /= (float)(e6 - s6);
            v = (v >= 0.0f) ? v : 0.1f * v;
            part += v * wfcL[k0 * 18 + 12 + i6];
        }
        partial[k0] = part;
    }
    __syncthreads();

    if (tid == 0) {
        out[b] = partial[0] + partial[1] + partial[2] +
                 partial[3] + partial[4] + partial[5];
    }
}

extern "C" void kernel_launch(void* const* d_in, const int* in_sizes, int n_in,
                              void* d_out, int out_size, void* d_ws, size_t ws_size,
                              hipStream_t stream) {
    // Robust input assignment by element count:
    //   x: B*2048*16, wa_k: 16*k (16..96), wb_k: k (1..6), wfc: 108
    const float* x = nullptr;
    const float* wa[6] = {nullptr};
    const float* wb[6] = {nullptr};
    const float* wfc = nullptr;
    int nb = 0;
    for (int i = 0; i < n_in; ++i) {
        const int sz = in_sizes[i];
        const float* p = (const float*)d_in[i];
        if (sz >= TLEN * NCH) { x = p; nb = sz / (TLEN * NCH); }
        else if (sz == 108)   { wfc = p; }
        else if (sz % NCH == 0 && sz >= NCH && sz <= 6 * NCH) { wa[sz / NCH - 1] = p; }
        else if (sz >= 1 && sz <= 6) { wb[sz - 1] = p; }
    }

    float* outp = (float*)d_out;
    dim3 grid(nb), block(NTHREADS);
    hipLaunchKernelGGL(filternet_kernel, grid, block, 0, stream,
                       x, wa[0], wa[1], wa[2], wa[3], wa[4], wa[5],
                       wb[0], wb[1], wb[2], wb[3], wb[4], wb[5],
                       wfc, outp, nb);
}

// Round 3
// 75.997 us; speedup vs baseline: 1.1354x; 1.0847x over previous
//
#include <hip/hip_runtime.h>

#define NCH 16          // feature channels F
#define TLEN 2048       // time length T
#define NTHREADS 256
#define TTPAD 20        // Tt row stride (floats): 16B-aligned, decent bank spread

// One block per batch element.
// Phases:
//  A : chunk sums (8 contiguous positions/thread) -> sA; threads owning a
//      cluster-window position ALSO write within-chunk partial prefixes -> Tt
//  B1: segment sums (16 chunks = 128 positions each)          -> sSeg[16][16]
//  C : Tt[p] += chunk-level prefix P[chunk_base(p)] (pure LDS) -> exact P[p]
//  D : 72 pooled stage-a values via prefix differences        -> faL[6][12]
//  E : stage-b conv + pool + leaky + FC                       -> out[b]
__global__ __launch_bounds__(NTHREADS, 4) void filternet_kernel(
    const float* __restrict__ x,
    const float* __restrict__ wa1, const float* __restrict__ wa2,
    const float* __restrict__ wa3, const float* __restrict__ wa4,
    const float* __restrict__ wa5, const float* __restrict__ wa6,
    const float* __restrict__ wb1, const float* __restrict__ wb2,
    const float* __restrict__ wb3, const float* __restrict__ wb4,
    const float* __restrict__ wb5, const float* __restrict__ wb6,
    const float* __restrict__ wfc, float* __restrict__ out, int nb)
{
    __shared__ float sA[NTHREADS][NCH + 1];   // chunk sums (8 pos), padded
    __shared__ float sSeg[16][NCH];           // segment sums (128 pos)
    __shared__ float Tt[13 * 16][TTPAD];      // window prefixes (phase A: partial)
    __shared__ float waL[6][NCH][6];
    __shared__ float wbL[6][6];
    __shared__ float wfcL[108];
    __shared__ float faL[6][12];
    __shared__ float partial[6];

    const int tid = threadIdx.x;
    const int b = blockIdx.x;
    if (b >= nb) return;
    const float* __restrict__ xb = x + (size_t)b * (TLEN * NCH);

    // ---- weights -> LDS (consumed in phases D/E; A->B1 barrier covers it)
    if (tid < 96) {
        const int k0 = tid >> 4, c = tid & 15, K = k0 + 1;
        const float* w = (k0 == 0) ? wa1 : (k0 == 1) ? wa2 : (k0 == 2) ? wa3
                       : (k0 == 3) ? wa4 : (k0 == 4) ? wa5 : wa6;
        for (int j = 0; j < 6; ++j)
            waL[k0][c][j] = (j < K) ? w[c * K + j] : 0.0f;
    } else if (tid < 102) {
        const int k0 = tid - 96, K = k0 + 1;
        const float* w = (k0 == 0) ? wb1 : (k0 == 1) ? wb2 : (k0 == 2) ? wb3
                       : (k0 == 3) ? wb4 : (k0 == 4) ? wb5 : wb6;
        for (int j = 0; j < 6; ++j)
            wbL[k0][j] = (j < K) ? w[j] : 0.0f;
    } else if (tid >= 128 && tid < 236) {
        wfcL[tid - 128] = wfc[tid - 128];
    }

    // ---- which cluster window (if any) intersects this thread's chunk?
    // windows: [cb_ci, cb_ci+16), cb spacing ~170 >> 8+16 -> at most one.
    const int a0 = tid * 8;
    int wci = -1, wcb = 0;
#pragma unroll
    for (int ci = 0; ci < 13; ++ci) {
        const int cb = (ci == 0) ? 0 : (ci * 2043) / 12 - 1;  // compile-time
        if (a0 + 8 > cb && a0 < cb + 16) { wci = ci; wcb = cb; }
    }

    // ---- phase A: chunk sums + in-window partial prefixes
    {
        float accv[NCH];
#pragma unroll
        for (int c = 0; c < NCH; ++c) accv[c] = 0.0f;
        const float4* x4 = reinterpret_cast<const float4*>(xb) + (size_t)tid * 32;
#pragma unroll
        for (int u = 0; u < 8; ++u) {
            // partial prefix BEFORE adding position p = a0+u:
            // Tt[ci*16+off] = sum_{t=chunk_start}^{p-1} x[t][:]
            if (wci >= 0) {
                const int off = a0 + u - wcb;
                if (off >= 0 && off < 16) {
                    float4* dst = reinterpret_cast<float4*>(&Tt[wci * 16 + off][0]);
                    dst[0] = make_float4(accv[0], accv[1], accv[2], accv[3]);
                    dst[1] = make_float4(accv[4], accv[5], accv[6], accv[7]);
                    dst[2] = make_float4(accv[8], accv[9], accv[10], accv[11]);
                    dst[3] = make_float4(accv[12], accv[13], accv[14], accv[15]);
                }
            }
#pragma unroll
            for (int g = 0; g < 4; ++g) {
                float4 v = x4[u * 4 + g];
                accv[g * 4 + 0] += v.x;
                accv[g * 4 + 1] += v.y;
                accv[g * 4 + 2] += v.z;
                accv[g * 4 + 3] += v.w;
            }
        }
#pragma unroll
        for (int c = 0; c < NCH; ++c) sA[tid][c] = accv[c];
    }
    __syncthreads();

    // ---- phase B1: segment sums (16 chunks each)
    {
        const int s = tid >> 4, c = tid & 15;
        float v = 0.0f;
#pragma unroll
        for (int u = 0; u < 16; ++u) v += sA[s * 16 + u][c];
        sSeg[s][c] = v;
    }
    __syncthreads();

    // ---- phase C: add chunk-level prefix to each window entry (pure LDS)
    if (tid < 13 * 16) {
        const int ci = tid >> 4, c = tid & 15;
        const int cb = (ci == 0) ? 0 : (ci * 2043) / 12 - 1;
        const int j0 = cb >> 3;     // chunk containing cb
        const int sb = j0 >> 4;     // segments fully below
        float run = 0.0f;
        for (int s = 0; s < sb; ++s) run += sSeg[s][c];
        for (int j = sb * 16; j < j0; ++j) run += sA[j][c];
        // run == P[j0*8][c]
        int cur = j0;
#pragma unroll
        for (int off = 0; off < 16; ++off) {
            const int p = cb + off;
            const int pj = (p < TLEN) ? (p >> 3) : 256;
            while (cur < pj) { run += sA[cur][c]; ++cur; }
            if (p < TLEN) Tt[ci * 16 + off][c] += run;   // partial + P[chunk base]
            else          Tt[ci * 16 + off][c] = run;    // P[TLEN] (no owner wrote)
        }
    }
    __syncthreads();

    // ---- phase D: 72 pooled stage-a values
    // pooled_sum[k][i] = sum_j sum_c wa_k[c,j]*(P[e+j][c]-P[s+j][c])
    if (tid < 72) {
        const int k0 = tid / 12, i = tid % 12, K = k0 + 1;
        const int L = TLEN - k0;
        const int s = (i * L) / 12;
        const int e = ((i + 1) * L + 11) / 12;   // ceil((i+1)L/12)
        const int n = e - s;
        const int cbs = (i == 0) ? 0 : (i * 2043) / 12 - 1;
        const int cbe = ((i + 1) * 2043) / 12 - 1;
        const int rs = i * 16 + (s - cbs);
        const int re = (i + 1) * 16 + (e - cbe);
        float acc2 = 0.0f;
        for (int j = 0; j < K; ++j) {
#pragma unroll
            for (int c = 0; c < NCH; ++c)
                acc2 += waL[k0][c][j] * (Tt[re + j][c] - Tt[rs + j][c]);
        }
        float v = acc2 / (float)n;
        faL[k0][i] = (v >= 0.0f) ? v : 0.1f * v;
    }
    __syncthreads();

    // ---- phase E: stage-b conv(dil=2) + pool(lb->6) + leaky + FC partials
    if (tid < 6) {
        const int k0 = tid, K = k0 + 1;
        const int lb = 12 - 2 * k0;
        float fbv[12];
        for (int l = 0; l < lb; ++l) {
            float a = 0.0f;
            for (int j = 0; j < K; ++j) a += wbL[k0][j] * faL[k0][l + 2 * j];
            fbv[l] = a;
        }
        float part = 0.0f;
        for (int i2 = 0; i2 < 12; ++i2)
            part += faL[k0][i2] * wfcL[k0 * 18 + i2];
        for (int i6 = 0; i6 < 6; ++i6) {
            const int s6 = (i6 * lb) / 6;
            const int e6 = ((i6 + 1) * lb + 5) / 6;
            float v = 0.0f;
            for (int l = s6; l < e6; ++l) v += fbv[l];
            v /= (float)(e6 - s6);
            v = (v >= 0.0f) ? v : 0.1f * v;
            part += v * wfcL[k0 * 18 + 12 + i6];
        }
        partial[k0] = part;
    }
    __syncthreads();

    if (tid == 0) {
        out[b] = partial[0] + partial[1] + partial[2] +
                 partial[3] + partial[4] + partial[5];
    }
}

extern "C" void kernel_launch(void* const* d_in, const int* in_sizes, int n_in,
                              void* d_out, int out_size, void* d_ws, size_t ws_size,
                              hipStream_t stream) {
    // Robust input assignment by element count:
    //   x: B*2048*16, wa_k: 16*k (16..96), wb_k: k (1..6), wfc: 108
    const float* x = nullptr;
    const float* wa[6] = {nullptr};
    const float* wb[6] = {nullptr};
    const float* wfc = nullptr;
    int nb = 0;
    for (int i = 0; i < n_in; ++i) {
        const int sz = in_sizes[i];
        const float* p = (const float*)d_in[i];
        if (sz >= TLEN * NCH) { x = p; nb = sz / (TLEN * NCH); }
        else if (sz == 108)   { wfc = p; }
        else if (sz % NCH == 0 && sz >= NCH && sz <= 6 * NCH) { wa[sz / NCH - 1] = p; }
        else if (sz >= 1 && sz <= 6) { wb[sz - 1] = p; }
    }

    float* outp = (float*)d_out;
    dim3 grid(nb), block(NTHREADS);
    hipLaunchKernelGGL(filternet_kernel, grid, block, 0, stream,
                       x, wa[0], wa[1], wa[2], wa[3], wa[4], wa[5],
                       wb[0], wb[1], wb[2], wb[3], wb[4], wb[5],
                       wfc, outp, nb);
}